// Round 1
// baseline (6120.742 us; speedup 1.0000x reference)
//
#include <hip/hip_runtime.h>
#include <math.h>

#define N_NODES 50000
#define N_EDGES 1600000
#define DIM 64
#define HEADS 8
#define EDGE_DIM 32

// ---------------- K1: Q/K/V node projections ----------------
// One wave (64 lanes) per node; lane l computes output column l for Q,K,V.
// Weights staged in LDS (48 KB); x-row broadcast via __shfl.
__global__ __launch_bounds__(256) void qkv_proj(
    const float* __restrict__ x,
    const float* __restrict__ WQ, const float* __restrict__ bQ,
    const float* __restrict__ WK, const float* __restrict__ bK,
    const float* __restrict__ WV, const float* __restrict__ bV,
    float* __restrict__ Q, float* __restrict__ K, float* __restrict__ V)
{
    __shared__ float sWQ[DIM * DIM];
    __shared__ float sWK[DIM * DIM];
    __shared__ float sWV[DIM * DIM];
    for (int t = threadIdx.x; t < DIM * DIM; t += blockDim.x) {
        sWQ[t] = WQ[t]; sWK[t] = WK[t]; sWV[t] = WV[t];
    }
    __syncthreads();
    const int lane = threadIdx.x & 63;
    const int wave = threadIdx.x >> 6;
    const int wpb  = blockDim.x >> 6;
    const float bq = bQ[lane], bk = bK[lane], bv = bV[lane];
    for (int n = blockIdx.x * wpb + wave; n < N_NODES; n += gridDim.x * wpb) {
        float xl = x[(size_t)n * DIM + lane];
        float aq = bq, ak = bk, av = bv;
        #pragma unroll
        for (int k = 0; k < DIM; ++k) {
            float xv = __shfl(xl, k, 64);
            aq += xv * sWQ[k * DIM + lane];
            ak += xv * sWK[k * DIM + lane];
            av += xv * sWV[k * DIM + lane];
        }
        Q[(size_t)n * DIM + lane] = aq;
        K[(size_t)n * DIM + lane] = ak;
        V[(size_t)n * DIM + lane] = av;
    }
}

// ---------------- K2: per-edge scores -> e = exp(score), ssum atomics ----------------
// One thread per edge. Edge MLP (32 -> 32 SiLU -> 8) with weights in LDS,
// Q[j]/K[i] gathers are 256B contiguous (L2/L3-resident arrays).
// No max-subtraction: scores are O(1), exp never overflows; alpha identical.
__global__ __launch_bounds__(256) void edge_scores(
    const int* __restrict__ ei,
    const float* __restrict__ edge_attr,
    const float* __restrict__ We1, const float* __restrict__ be1,
    const float* __restrict__ We2, const float* __restrict__ be2,
    const float* __restrict__ Q, const float* __restrict__ K,
    float* __restrict__ evals, float* __restrict__ ssum)
{
    __shared__ float sW1[EDGE_DIM * EDGE_DIM];
    __shared__ float sW2[EDGE_DIM * HEADS];
    __shared__ float sb1[EDGE_DIM];
    __shared__ float sb2[HEADS];
    for (int t = threadIdx.x; t < EDGE_DIM * EDGE_DIM; t += blockDim.x) sW1[t] = We1[t];
    for (int t = threadIdx.x; t < EDGE_DIM * HEADS; t += blockDim.x) sW2[t] = We2[t];
    if (threadIdx.x < EDGE_DIM) sb1[threadIdx.x] = be1[threadIdx.x];
    if (threadIdx.x < HEADS)    sb2[threadIdx.x] = be2[threadIdx.x];
    __syncthreads();
    const float inv_sqrt_dk = 0.35355339059327373f;  // 1/sqrt(8)
    for (int e = blockIdx.x * blockDim.x + threadIdx.x; e < N_EDGES;
         e += gridDim.x * blockDim.x) {
        const int i = ei[e];
        const int j = ei[N_EDGES + e];
        // load edge_attr row (128 B, float4 x8)
        float a[EDGE_DIM];
        const float4* ar = (const float4*)(edge_attr + (size_t)e * EDGE_DIM);
        #pragma unroll
        for (int q = 0; q < EDGE_DIM / 4; ++q) {
            float4 v = ar[q];
            a[q * 4 + 0] = v.x; a[q * 4 + 1] = v.y;
            a[q * 4 + 2] = v.z; a[q * 4 + 3] = v.w;
        }
        // MLP: bias[h] = be2[h] + sum_c silu(a . We1[:,c] + be1[c]) * We2[c][h]
        float bias[HEADS];
        #pragma unroll
        for (int h = 0; h < HEADS; ++h) bias[h] = sb2[h];
        #pragma unroll 4
        for (int c = 0; c < EDGE_DIM; ++c) {
            float s = sb1[c];
            #pragma unroll
            for (int k = 0; k < EDGE_DIM; ++k) s += a[k] * sW1[k * EDGE_DIM + c];
            const float sil = s / (1.0f + __expf(-s));
            #pragma unroll
            for (int h = 0; h < HEADS; ++h) bias[h] += sil * sW2[c * HEADS + h];
        }
        // per-head dot(Q[j], K[i])
        const float4* Qr = (const float4*)(Q + (size_t)j * DIM);
        const float4* Kr = (const float4*)(K + (size_t)i * DIM);
        float ev[HEADS];
        #pragma unroll
        for (int h = 0; h < HEADS; ++h) {
            float4 q0 = Qr[h * 2], q1 = Qr[h * 2 + 1];
            float4 k0 = Kr[h * 2], k1 = Kr[h * 2 + 1];
            float dot = q0.x * k0.x + q0.y * k0.y + q0.z * k0.z + q0.w * k0.w
                      + q1.x * k1.x + q1.y * k1.y + q1.z * k1.z + q1.w * k1.w;
            float s = dot * inv_sqrt_dk + bias[h];
            float ex = __expf(s);
            ev[h] = ex;
            atomicAdd(&ssum[(size_t)j * HEADS + h], ex);
        }
        float4* er = (float4*)(evals + (size_t)e * HEADS);
        er[0] = make_float4(ev[0], ev[1], ev[2], ev[3]);
        er[1] = make_float4(ev[4], ev[5], ev[6], ev[7]);
    }
}

// ---------------- K3: alpha = e/ssum[j]; attn[j] += alpha * V[i] ----------------
__global__ __launch_bounds__(256) void edge_accum(
    const int* __restrict__ ei,
    const float* __restrict__ evals, const float* __restrict__ ssum,
    const float* __restrict__ V, float* __restrict__ attn)
{
    for (int e = blockIdx.x * blockDim.x + threadIdx.x; e < N_EDGES;
         e += gridDim.x * blockDim.x) {
        const int i = ei[e];
        const int j = ei[N_EDGES + e];
        const float4* er = (const float4*)(evals + (size_t)e * HEADS);
        float4 e0 = er[0], e1 = er[1];
        const float* sr = ssum + (size_t)j * HEADS;
        float al[HEADS];
        al[0] = e0.x / (sr[0] + 1e-12f);
        al[1] = e0.y / (sr[1] + 1e-12f);
        al[2] = e0.z / (sr[2] + 1e-12f);
        al[3] = e0.w / (sr[3] + 1e-12f);
        al[4] = e1.x / (sr[4] + 1e-12f);
        al[5] = e1.y / (sr[5] + 1e-12f);
        al[6] = e1.z / (sr[6] + 1e-12f);
        al[7] = e1.w / (sr[7] + 1e-12f);
        const float4* Vr = (const float4*)(V + (size_t)i * DIM);
        float* arow = attn + (size_t)j * DIM;
        #pragma unroll
        for (int h = 0; h < HEADS; ++h) {
            float4 v0 = Vr[h * 2], v1 = Vr[h * 2 + 1];
            const float alv = al[h];
            atomicAdd(&arow[h * 8 + 0], alv * v0.x);
            atomicAdd(&arow[h * 8 + 1], alv * v0.y);
            atomicAdd(&arow[h * 8 + 2], alv * v0.z);
            atomicAdd(&arow[h * 8 + 3], alv * v0.w);
            atomicAdd(&arow[h * 8 + 4], alv * v1.x);
            atomicAdd(&arow[h * 8 + 5], alv * v1.y);
            atomicAdd(&arow[h * 8 + 6], alv * v1.z);
            atomicAdd(&arow[h * 8 + 7], alv * v1.w);
        }
    }
}

// ---------------- K4: out = attn @ WO + bO ----------------
__global__ __launch_bounds__(256) void out_proj(
    const float* __restrict__ attn,
    const float* __restrict__ WO, const float* __restrict__ bO,
    float* __restrict__ out)
{
    __shared__ float sW[DIM * DIM];
    for (int t = threadIdx.x; t < DIM * DIM; t += blockDim.x) sW[t] = WO[t];
    __syncthreads();
    const int lane = threadIdx.x & 63;
    const int wave = threadIdx.x >> 6;
    const int wpb  = blockDim.x >> 6;
    const float bo = bO[lane];
    for (int n = blockIdx.x * wpb + wave; n < N_NODES; n += gridDim.x * wpb) {
        float xl = attn[(size_t)n * DIM + lane];
        float acc = bo;
        #pragma unroll
        for (int k = 0; k < DIM; ++k) {
            float xv = __shfl(xl, k, 64);
            acc += xv * sW[k * DIM + lane];
        }
        out[(size_t)n * DIM + lane] = acc;
    }
}

extern "C" void kernel_launch(void* const* d_in, const int* in_sizes, int n_in,
                              void* d_out, int out_size, void* d_ws, size_t ws_size,
                              hipStream_t stream) {
    const float* x    = (const float*)d_in[0];
    const int*   ei   = (const int*)d_in[1];
    const float* ea   = (const float*)d_in[2];
    const float* WQ   = (const float*)d_in[3];
    const float* bQ   = (const float*)d_in[4];
    const float* WK   = (const float*)d_in[5];
    const float* bK   = (const float*)d_in[6];
    const float* WV   = (const float*)d_in[7];
    const float* bV   = (const float*)d_in[8];
    const float* WO   = (const float*)d_in[9];
    const float* bO   = (const float*)d_in[10];
    const float* We1  = (const float*)d_in[11];
    const float* be1  = (const float*)d_in[12];
    const float* We2  = (const float*)d_in[13];
    const float* be2  = (const float*)d_in[14];
    float* out = (float*)d_out;

    float* ws = (float*)d_ws;
    size_t off = 0;
    float* Q     = ws + off; off += (size_t)N_NODES * DIM;
    float* K     = ws + off; off += (size_t)N_NODES * DIM;
    float* V     = ws + off; off += (size_t)N_NODES * DIM;
    float* attn  = ws + off; off += (size_t)N_NODES * DIM;
    float* ssum  = ws + off; off += (size_t)N_NODES * HEADS;
    float* evals = ws + off; off += (size_t)N_EDGES * HEADS;

    // zero the accumulators every call (harness does not re-poison between replays)
    hipMemsetAsync(ssum, 0, (size_t)N_NODES * HEADS * sizeof(float), stream);
    hipMemsetAsync(attn, 0, (size_t)N_NODES * DIM * sizeof(float), stream);

    qkv_proj<<<2048, 256, 0, stream>>>(x, WQ, bQ, WK, bK, WV, bV, Q, K, V);
    edge_scores<<<4096, 256, 0, stream>>>(ei, ea, We1, be1, We2, be2, Q, K, evals, ssum);
    edge_accum<<<4096, 256, 0, stream>>>(ei, evals, ssum, V, attn);
    out_proj<<<2048, 256, 0, stream>>>(attn, WO, bO, out);
}

// Round 2
// 696.757 us; speedup vs baseline: 8.7846x; 8.7846x over previous
//
#include <hip/hip_runtime.h>
#include <math.h>

#define N_NODES 50000
#define N_EDGES 1600000
#define DIM 64
#define HEADS 8
#define EDGE_DIM 32

// ---------------- K0a: histogram of destination degrees ----------------
__global__ __launch_bounds__(256) void count_deg(
    const int* __restrict__ ei, int* __restrict__ deg)
{
    for (int e = blockIdx.x * blockDim.x + threadIdx.x; e < N_EDGES;
         e += gridDim.x * blockDim.x) {
        atomicAdd(&deg[ei[N_EDGES + e]], 1);
    }
}

// ---------------- K0b: exclusive scan deg -> off (single workgroup) ----------------
__global__ __launch_bounds__(1024) void scan_deg(
    const int* __restrict__ deg, int* __restrict__ off)
{
    __shared__ int s[1024];
    __shared__ int carry_s;
    if (threadIdx.x == 0) { carry_s = 0; off[0] = 0; }
    __syncthreads();
    for (int base = 0; base < N_NODES; base += 1024) {
        const int idx = base + threadIdx.x;
        s[threadIdx.x] = (idx < N_NODES) ? deg[idx] : 0;
        __syncthreads();
        for (int o = 1; o < 1024; o <<= 1) {
            int t = (threadIdx.x >= o) ? s[threadIdx.x - o] : 0;
            __syncthreads();
            s[threadIdx.x] += t;
            __syncthreads();
        }
        const int carry = carry_s;
        if (idx < N_NODES) off[idx + 1] = carry + s[threadIdx.x];
        __syncthreads();
        if (threadIdx.x == 0) carry_s = carry + s[1023];
        __syncthreads();
    }
}

// ---------------- K1: Q/K/V node projections ----------------
__global__ __launch_bounds__(256) void qkv_proj(
    const float* __restrict__ x,
    const float* __restrict__ WQ, const float* __restrict__ bQ,
    const float* __restrict__ WK, const float* __restrict__ bK,
    const float* __restrict__ WV, const float* __restrict__ bV,
    float* __restrict__ Q, float* __restrict__ K, float* __restrict__ V)
{
    __shared__ float sWQ[DIM * DIM];
    __shared__ float sWK[DIM * DIM];
    __shared__ float sWV[DIM * DIM];
    for (int t = threadIdx.x; t < DIM * DIM; t += blockDim.x) {
        sWQ[t] = WQ[t]; sWK[t] = WK[t]; sWV[t] = WV[t];
    }
    __syncthreads();
    const int lane = threadIdx.x & 63;
    const int wave = threadIdx.x >> 6;
    const int wpb  = blockDim.x >> 6;
    const float bq = bQ[lane], bk = bK[lane], bv = bV[lane];
    for (int n = blockIdx.x * wpb + wave; n < N_NODES; n += gridDim.x * wpb) {
        float xl = x[(size_t)n * DIM + lane];
        float aq = bq, ak = bk, av = bv;
        #pragma unroll
        for (int k = 0; k < DIM; ++k) {
            float xv = __shfl(xl, k, 64);
            aq += xv * sWQ[k * DIM + lane];
            ak += xv * sWK[k * DIM + lane];
            av += xv * sWV[k * DIM + lane];
        }
        Q[(size_t)n * DIM + lane] = aq;
        K[(size_t)n * DIM + lane] = ak;
        V[(size_t)n * DIM + lane] = av;
    }
}

// ---------------- K2: per-edge scores -> exp, scattered to CSR position ----------------
// e-values written directly to sorted-by-destination position p; no float atomics.
// Normalization folded into node_gather (num/den), so no ssum pass at all.
__global__ __launch_bounds__(256) void edge_scores(
    const int* __restrict__ ei,
    const float* __restrict__ edge_attr,
    const float* __restrict__ We1, const float* __restrict__ be1,
    const float* __restrict__ We2, const float* __restrict__ be2,
    const float* __restrict__ Q, const float* __restrict__ K,
    const int* __restrict__ off, int* __restrict__ cursor,
    float* __restrict__ evals_sorted, int* __restrict__ src_sorted)
{
    __shared__ float sW1[EDGE_DIM * EDGE_DIM];
    __shared__ float sW2[EDGE_DIM * HEADS];
    __shared__ float sb1[EDGE_DIM];
    __shared__ float sb2[HEADS];
    for (int t = threadIdx.x; t < EDGE_DIM * EDGE_DIM; t += blockDim.x) sW1[t] = We1[t];
    for (int t = threadIdx.x; t < EDGE_DIM * HEADS; t += blockDim.x) sW2[t] = We2[t];
    if (threadIdx.x < EDGE_DIM) sb1[threadIdx.x] = be1[threadIdx.x];
    if (threadIdx.x < HEADS)    sb2[threadIdx.x] = be2[threadIdx.x];
    __syncthreads();
    const float inv_sqrt_dk = 0.35355339059327373f;  // 1/sqrt(8)
    for (int e = blockIdx.x * blockDim.x + threadIdx.x; e < N_EDGES;
         e += gridDim.x * blockDim.x) {
        const int i = ei[e];
        const int j = ei[N_EDGES + e];
        float a[EDGE_DIM];
        const float4* ar = (const float4*)(edge_attr + (size_t)e * EDGE_DIM);
        #pragma unroll
        for (int q = 0; q < EDGE_DIM / 4; ++q) {
            float4 v = ar[q];
            a[q * 4 + 0] = v.x; a[q * 4 + 1] = v.y;
            a[q * 4 + 2] = v.z; a[q * 4 + 3] = v.w;
        }
        float bias[HEADS];
        #pragma unroll
        for (int h = 0; h < HEADS; ++h) bias[h] = sb2[h];
        #pragma unroll 4
        for (int c = 0; c < EDGE_DIM; ++c) {
            float s = sb1[c];
            #pragma unroll
            for (int k = 0; k < EDGE_DIM; ++k) s += a[k] * sW1[k * EDGE_DIM + c];
            const float sil = s / (1.0f + __expf(-s));
            #pragma unroll
            for (int h = 0; h < HEADS; ++h) bias[h] += sil * sW2[c * HEADS + h];
        }
        const float4* Qr = (const float4*)(Q + (size_t)j * DIM);
        const float4* Kr = (const float4*)(K + (size_t)i * DIM);
        float ev[HEADS];
        #pragma unroll
        for (int h = 0; h < HEADS; ++h) {
            float4 q0 = Qr[h * 2], q1 = Qr[h * 2 + 1];
            float4 k0 = Kr[h * 2], k1 = Kr[h * 2 + 1];
            float dot = q0.x * k0.x + q0.y * k0.y + q0.z * k0.z + q0.w * k0.w
                      + q1.x * k1.x + q1.y * k1.y + q1.z * k1.z + q1.w * k1.w;
            ev[h] = __expf(dot * inv_sqrt_dk + bias[h]);
        }
        // scatter into destination-sorted position (int atomic on cursor only)
        const int p = off[j] + atomicAdd(&cursor[j], 1);
        src_sorted[p] = i;
        float4* er = (float4*)(evals_sorted + (size_t)p * HEADS);
        er[0] = make_float4(ev[0], ev[1], ev[2], ev[3]);
        er[1] = make_float4(ev[4], ev[5], ev[6], ev[7]);
    }
}

// ---------------- K3: per-node gather: attn[j] = (sum e_h * V[i]) / (sum e_h) ----------------
// One wave per destination node; lane = output dim; zero atomics.
__global__ __launch_bounds__(256) void node_gather(
    const int* __restrict__ off,
    const int* __restrict__ src_sorted,
    const float* __restrict__ evals_sorted,
    const float* __restrict__ V,
    float* __restrict__ attn)
{
    const int lane = threadIdx.x & 63;
    const int wave = threadIdx.x >> 6;
    const int j = blockIdx.x * (blockDim.x >> 6) + wave;
    if (j >= N_NODES) return;
    const int beg = off[j], end = off[j + 1];
    const int h = lane >> 3;  // head for this lane
    float num = 0.0f;
    float den = 1e-12f;
    int t = beg;
    for (; t + 3 < end; t += 4) {
        const int i0 = src_sorted[t + 0];
        const int i1 = src_sorted[t + 1];
        const int i2 = src_sorted[t + 2];
        const int i3 = src_sorted[t + 3];
        const float e0 = evals_sorted[(size_t)(t + 0) * HEADS + h];
        const float e1 = evals_sorted[(size_t)(t + 1) * HEADS + h];
        const float e2 = evals_sorted[(size_t)(t + 2) * HEADS + h];
        const float e3 = evals_sorted[(size_t)(t + 3) * HEADS + h];
        const float v0 = V[(size_t)i0 * DIM + lane];
        const float v1 = V[(size_t)i1 * DIM + lane];
        const float v2 = V[(size_t)i2 * DIM + lane];
        const float v3 = V[(size_t)i3 * DIM + lane];
        num += e0 * v0 + e1 * v1 + e2 * v2 + e3 * v3;
        den += e0 + e1 + e2 + e3;
    }
    for (; t < end; ++t) {
        const int i = src_sorted[t];
        const float ev = evals_sorted[(size_t)t * HEADS + h];
        num += ev * V[(size_t)i * DIM + lane];
        den += ev;
    }
    attn[(size_t)j * DIM + lane] = num / den;
}

// ---------------- K4: out = attn @ WO + bO ----------------
__global__ __launch_bounds__(256) void out_proj(
    const float* __restrict__ attn,
    const float* __restrict__ WO, const float* __restrict__ bO,
    float* __restrict__ out)
{
    __shared__ float sW[DIM * DIM];
    for (int t = threadIdx.x; t < DIM * DIM; t += blockDim.x) sW[t] = WO[t];
    __syncthreads();
    const int lane = threadIdx.x & 63;
    const int wave = threadIdx.x >> 6;
    const int wpb  = blockDim.x >> 6;
    const float bo = bO[lane];
    for (int n = blockIdx.x * wpb + wave; n < N_NODES; n += gridDim.x * wpb) {
        float xl = attn[(size_t)n * DIM + lane];
        float acc = bo;
        #pragma unroll
        for (int k = 0; k < DIM; ++k) {
            float xv = __shfl(xl, k, 64);
            acc += xv * sW[k * DIM + lane];
        }
        out[(size_t)n * DIM + lane] = acc;
    }
}

extern "C" void kernel_launch(void* const* d_in, const int* in_sizes, int n_in,
                              void* d_out, int out_size, void* d_ws, size_t ws_size,
                              hipStream_t stream) {
    const float* x    = (const float*)d_in[0];
    const int*   ei   = (const int*)d_in[1];
    const float* ea   = (const float*)d_in[2];
    const float* WQ   = (const float*)d_in[3];
    const float* bQ   = (const float*)d_in[4];
    const float* WK   = (const float*)d_in[5];
    const float* bK   = (const float*)d_in[6];
    const float* WV   = (const float*)d_in[7];
    const float* bV   = (const float*)d_in[8];
    const float* WO   = (const float*)d_in[9];
    const float* bO   = (const float*)d_in[10];
    const float* We1  = (const float*)d_in[11];
    const float* be1  = (const float*)d_in[12];
    const float* We2  = (const float*)d_in[13];
    const float* be2  = (const float*)d_in[14];
    float* out = (float*)d_out;

    char* ws = (char*)d_ws;
    size_t off_b = 0;
    auto alloc = [&](size_t bytes) {
        void* p = ws + off_b;
        off_b += (bytes + 255) & ~(size_t)255;  // 256B align
        return p;
    };
    float* Q            = (float*)alloc((size_t)N_NODES * DIM * sizeof(float));
    float* K            = (float*)alloc((size_t)N_NODES * DIM * sizeof(float));
    float* V            = (float*)alloc((size_t)N_NODES * DIM * sizeof(float));
    float* attn         = (float*)alloc((size_t)N_NODES * DIM * sizeof(float));
    float* evals_sorted = (float*)alloc((size_t)N_EDGES * HEADS * sizeof(float));
    int*   src_sorted   = (int*)  alloc((size_t)N_EDGES * sizeof(int));
    int*   deg          = (int*)  alloc((size_t)N_NODES * sizeof(int));
    int*   offs         = (int*)  alloc((size_t)(N_NODES + 1) * sizeof(int));
    int*   cursor       = (int*)  alloc((size_t)N_NODES * sizeof(int));

    hipMemsetAsync(deg,    0, (size_t)N_NODES * sizeof(int), stream);
    hipMemsetAsync(cursor, 0, (size_t)N_NODES * sizeof(int), stream);

    count_deg<<<2048, 256, 0, stream>>>(ei, deg);
    scan_deg<<<1, 1024, 0, stream>>>(deg, offs);
    qkv_proj<<<2048, 256, 0, stream>>>(x, WQ, bQ, WK, bK, WV, bV, Q, K, V);
    edge_scores<<<4096, 256, 0, stream>>>(ei, ea, We1, be1, We2, be2, Q, K,
                                          offs, cursor, evals_sorted, src_sorted);
    node_gather<<<(N_NODES + 3) / 4, 256, 0, stream>>>(offs, src_sorted,
                                                       evals_sorted, V, attn);
    out_proj<<<2048, 256, 0, stream>>>(attn, WO, bO, out);
}

// Round 3
// 479.237 us; speedup vs baseline: 12.7718x; 1.4539x over previous
//
#include <hip/hip_runtime.h>
#include <math.h>

#define N_NODES 50000
#define N_EDGES 1600000
#define DIM 64
#define HEADS 8
#define EDGE_DIM 32
#define SCAN_NBLK 49  // ceil(50000/1024)

// ---------------- K0a: histogram of destination degrees ----------------
__global__ __launch_bounds__(256) void count_deg(
    const int* __restrict__ ei, int* __restrict__ deg)
{
    const int e = blockIdx.x * 256 + threadIdx.x;
    if (e < N_EDGES) atomicAdd(&deg[ei[N_EDGES + e]], 1);
}

// ---------------- K0b: hierarchical exclusive scan ----------------
// local inclusive scan per 1024-block; block totals to part[]
__global__ __launch_bounds__(1024) void scan_local(
    const int* __restrict__ deg, int* __restrict__ off, int* __restrict__ part)
{
    __shared__ int s[1024];
    const int tid = threadIdx.x;
    const int idx = blockIdx.x * 1024 + tid;
    s[tid] = (idx < N_NODES) ? deg[idx] : 0;
    __syncthreads();
    for (int o = 1; o < 1024; o <<= 1) {
        int t = (tid >= o) ? s[tid - o] : 0;
        __syncthreads();
        s[tid] += t;
        __syncthreads();
    }
    if (idx < N_NODES) off[idx + 1] = s[tid];  // local inclusive, carry added later
    if (tid == 1023) part[blockIdx.x] = s[1023];
}

// single-wave exclusive scan of the 49 block totals
__global__ __launch_bounds__(64) void scan_part(int* __restrict__ part)
{
    const int lane = threadIdx.x;
    int v = (lane < SCAN_NBLK) ? part[lane] : 0;
    const int orig = v;
    for (int o = 1; o < 64; o <<= 1) {
        int t = __shfl_up(v, o, 64);
        if (lane >= o) v += t;
    }
    if (lane < SCAN_NBLK) part[lane] = v - orig;  // exclusive carry
}

// add carries; also produce woff (working cursor copy, consumed by scatter atomics)
__global__ __launch_bounds__(1024) void scan_add(
    const int* __restrict__ part, int* __restrict__ off, int* __restrict__ woff)
{
    const int idx = blockIdx.x * 1024 + threadIdx.x;
    if (idx == 0) { off[0] = 0; woff[0] = 0; }
    if (idx < N_NODES) {
        const int val = off[idx + 1] + part[blockIdx.x];
        off[idx + 1] = val;
        if (idx + 1 < N_NODES) woff[idx + 1] = val;
    }
}

// ---------------- K1: Q/K/V node projections ----------------
__global__ __launch_bounds__(256) void qkv_proj(
    const float* __restrict__ x,
    const float* __restrict__ WQ, const float* __restrict__ bQ,
    const float* __restrict__ WK, const float* __restrict__ bK,
    const float* __restrict__ WV, const float* __restrict__ bV,
    float* __restrict__ Q, float* __restrict__ K, float* __restrict__ V)
{
    __shared__ float sWQ[DIM * DIM];
    __shared__ float sWK[DIM * DIM];
    __shared__ float sWV[DIM * DIM];
    for (int t = threadIdx.x; t < DIM * DIM; t += blockDim.x) {
        sWQ[t] = WQ[t]; sWK[t] = WK[t]; sWV[t] = WV[t];
    }
    __syncthreads();
    const int lane = threadIdx.x & 63;
    const int wave = threadIdx.x >> 6;
    const int n = blockIdx.x * 4 + wave;
    if (n >= N_NODES) return;
    float xl = x[(size_t)n * DIM + lane];
    float aq = bQ[lane], ak = bK[lane], av = bV[lane];
    #pragma unroll
    for (int k = 0; k < DIM; ++k) {
        float xv = __shfl(xl, k, 64);
        aq += xv * sWQ[k * DIM + lane];
        ak += xv * sWK[k * DIM + lane];
        av += xv * sWV[k * DIM + lane];
    }
    Q[(size_t)n * DIM + lane] = aq;
    K[(size_t)n * DIM + lane] = ak;
    V[(size_t)n * DIM + lane] = av;
}

// ---------------- K2: per-edge MLP bias, scattered to CSR position ----------------
// Streaming-only: no Q/K access here. Writes {src node, bias[8]} at sorted position.
__global__ __launch_bounds__(256) void edge_mlp_scatter(
    const int* __restrict__ ei,
    const float* __restrict__ edge_attr,
    const float* __restrict__ We1, const float* __restrict__ be1,
    const float* __restrict__ We2, const float* __restrict__ be2,
    int* __restrict__ woff,
    float* __restrict__ bias_sorted, int* __restrict__ src_sorted)
{
    __shared__ float sW1[EDGE_DIM * EDGE_DIM];
    __shared__ float sW2[EDGE_DIM * HEADS];
    __shared__ float sb1[EDGE_DIM];
    __shared__ float sb2[HEADS];
    for (int t = threadIdx.x; t < EDGE_DIM * EDGE_DIM; t += 256) sW1[t] = We1[t];
    for (int t = threadIdx.x; t < EDGE_DIM * HEADS; t += 256) sW2[t] = We2[t];
    if (threadIdx.x < EDGE_DIM) sb1[threadIdx.x] = be1[threadIdx.x];
    if (threadIdx.x < HEADS)    sb2[threadIdx.x] = be2[threadIdx.x];
    __syncthreads();
    const int e = blockIdx.x * 256 + threadIdx.x;
    if (e >= N_EDGES) return;
    float a[EDGE_DIM];
    const float4* ar = (const float4*)(edge_attr + (size_t)e * EDGE_DIM);
    #pragma unroll
    for (int q = 0; q < EDGE_DIM / 4; ++q) {
        float4 v = ar[q];
        a[q * 4 + 0] = v.x; a[q * 4 + 1] = v.y;
        a[q * 4 + 2] = v.z; a[q * 4 + 3] = v.w;
    }
    float bias[HEADS];
    #pragma unroll
    for (int h = 0; h < HEADS; ++h) bias[h] = sb2[h];
    #pragma unroll 4
    for (int c = 0; c < EDGE_DIM; ++c) {
        float s = sb1[c];
        #pragma unroll
        for (int k = 0; k < EDGE_DIM; ++k) s += a[k] * sW1[k * EDGE_DIM + c];
        const float sil = s / (1.0f + __expf(-s));
        #pragma unroll
        for (int h = 0; h < HEADS; ++h) bias[h] += sil * sW2[c * HEADS + h];
    }
    const int i = ei[e];
    const int j = ei[N_EDGES + e];
    const int p = atomicAdd(&woff[j], 1);
    src_sorted[p] = i;
    float4* br = (float4*)(bias_sorted + (size_t)p * HEADS);
    br[0] = make_float4(bias[0], bias[1], bias[2], bias[3]);
    br[1] = make_float4(bias[4], bias[5], bias[6], bias[7]);
}

// ---------------- K3: per-node attention + fused output projection ----------------
// One wave per destination node, lane = dim. Q[j] read once; per edge:
// coalesced K[i]/V[i] row gathers, 8-lane shfl reduce per head, exp, accumulate.
__global__ __launch_bounds__(256) void node_attn_out(
    const int* __restrict__ off,
    const int* __restrict__ src_sorted,
    const float* __restrict__ bias_sorted,
    const float* __restrict__ Q, const float* __restrict__ K,
    const float* __restrict__ V,
    const float* __restrict__ WO, const float* __restrict__ bO,
    float* __restrict__ out)
{
    __shared__ float sWO[DIM * DIM];
    for (int t = threadIdx.x; t < DIM * DIM; t += 256) sWO[t] = WO[t];
    __syncthreads();
    const int lane = threadIdx.x & 63;
    const int wave = threadIdx.x >> 6;
    const int j = blockIdx.x * 4 + wave;
    if (j >= N_NODES) return;
    const int beg = off[j], end = off[j + 1];
    const int h = lane >> 3;
    const float qv = Q[(size_t)j * DIM + lane];
    const float inv_sqrt_dk = 0.35355339059327373f;
    float num = 0.0f;
    float den = 1e-12f;
    int t = beg;
    for (; t + 1 < end; t += 2) {
        const int i0 = src_sorted[t];
        const int i1 = src_sorted[t + 1];
        const float k0 = K[(size_t)i0 * DIM + lane];
        const float k1 = K[(size_t)i1 * DIM + lane];
        const float v0 = V[(size_t)i0 * DIM + lane];
        const float v1 = V[(size_t)i1 * DIM + lane];
        const float b0 = bias_sorted[(size_t)t * HEADS + h];
        const float b1 = bias_sorted[(size_t)(t + 1) * HEADS + h];
        float d0 = qv * k0;
        d0 += __shfl_xor(d0, 1, 64);
        d0 += __shfl_xor(d0, 2, 64);
        d0 += __shfl_xor(d0, 4, 64);
        float d1 = qv * k1;
        d1 += __shfl_xor(d1, 1, 64);
        d1 += __shfl_xor(d1, 2, 64);
        d1 += __shfl_xor(d1, 4, 64);
        const float e0 = __expf(d0 * inv_sqrt_dk + b0);
        const float e1 = __expf(d1 * inv_sqrt_dk + b1);
        num += e0 * v0 + e1 * v1;
        den += e0 + e1;
    }
    if (t < end) {
        const int i0 = src_sorted[t];
        const float k0 = K[(size_t)i0 * DIM + lane];
        const float v0 = V[(size_t)i0 * DIM + lane];
        const float b0 = bias_sorted[(size_t)t * HEADS + h];
        float d0 = qv * k0;
        d0 += __shfl_xor(d0, 1, 64);
        d0 += __shfl_xor(d0, 2, 64);
        d0 += __shfl_xor(d0, 4, 64);
        const float e0 = __expf(d0 * inv_sqrt_dk + b0);
        num += e0 * v0;
        den += e0;
    }
    const float av = num / den;
    // fused out-projection: out[j][lane] = bO[lane] + sum_k attn[j][k]*WO[k][lane]
    float acc = bO[lane];
    #pragma unroll
    for (int k = 0; k < DIM; ++k) {
        acc += __shfl(av, k, 64) * sWO[k * DIM + lane];
    }
    out[(size_t)j * DIM + lane] = acc;
}

extern "C" void kernel_launch(void* const* d_in, const int* in_sizes, int n_in,
                              void* d_out, int out_size, void* d_ws, size_t ws_size,
                              hipStream_t stream) {
    const float* x    = (const float*)d_in[0];
    const int*   ei   = (const int*)d_in[1];
    const float* ea   = (const float*)d_in[2];
    const float* WQ   = (const float*)d_in[3];
    const float* bQ   = (const float*)d_in[4];
    const float* WK   = (const float*)d_in[5];
    const float* bK   = (const float*)d_in[6];
    const float* WV   = (const float*)d_in[7];
    const float* bV   = (const float*)d_in[8];
    const float* WO   = (const float*)d_in[9];
    const float* bO   = (const float*)d_in[10];
    const float* We1  = (const float*)d_in[11];
    const float* be1  = (const float*)d_in[12];
    const float* We2  = (const float*)d_in[13];
    const float* be2  = (const float*)d_in[14];
    float* out = (float*)d_out;

    char* ws = (char*)d_ws;
    size_t off_b = 0;
    auto alloc = [&](size_t bytes) {
        void* p = ws + off_b;
        off_b += (bytes + 255) & ~(size_t)255;
        return p;
    };
    float* Q           = (float*)alloc((size_t)N_NODES * DIM * sizeof(float));
    float* K           = (float*)alloc((size_t)N_NODES * DIM * sizeof(float));
    float* V           = (float*)alloc((size_t)N_NODES * DIM * sizeof(float));
    float* bias_sorted = (float*)alloc((size_t)N_EDGES * HEADS * sizeof(float));
    int*   src_sorted  = (int*)  alloc((size_t)N_EDGES * sizeof(int));
    int*   deg         = (int*)  alloc((size_t)N_NODES * sizeof(int));
    int*   offs        = (int*)  alloc((size_t)(N_NODES + 1) * sizeof(int));
    int*   woff        = (int*)  alloc((size_t)N_NODES * sizeof(int));
    int*   part        = (int*)  alloc((size_t)SCAN_NBLK * sizeof(int));

    hipMemsetAsync(deg, 0, (size_t)N_NODES * sizeof(int), stream);

    count_deg<<<N_EDGES / 256, 256, 0, stream>>>(ei, deg);
    scan_local<<<SCAN_NBLK, 1024, 0, stream>>>(deg, offs, part);
    scan_part<<<1, 64, 0, stream>>>(part);
    scan_add<<<SCAN_NBLK, 1024, 0, stream>>>(part, offs, woff);
    qkv_proj<<<(N_NODES + 3) / 4, 256, 0, stream>>>(x, WQ, bQ, WK, bK, WV, bV, Q, K, V);
    edge_mlp_scatter<<<N_EDGES / 256, 256, 0, stream>>>(ei, ea, We1, be1, We2, be2,
                                                        woff, bias_sorted, src_sorted);
    node_attn_out<<<(N_NODES + 3) / 4, 256, 0, stream>>>(offs, src_sorted, bias_sorted,
                                                         Q, K, V, WO, bO, out);
}

// Round 4
// 442.614 us; speedup vs baseline: 13.8286x; 1.0827x over previous
//
#include <hip/hip_runtime.h>
#include <math.h>

#define N_NODES 50000
#define N_EDGES 1600000
#define DIM 64
#define HEADS 8
#define EDGE_DIM 32
#define SCAN_NBLK 49  // ceil(50000/1024)

// ---- bf16 helpers (RNE round via bit trick; inputs are finite) ----
__device__ __forceinline__ unsigned int f2bf(float f) {
    union { float f; unsigned int u; } c; c.f = f;
    unsigned int u = c.u;
    return (u + 0x7FFFu + ((u >> 16) & 1u)) >> 16;  // 16-bit bf16 value
}
__device__ __forceinline__ float bf_lo(unsigned int u) {  // low ushort -> float
    return __uint_as_float(u << 16);
}
__device__ __forceinline__ float bf_hi(unsigned int u) {  // high ushort -> float
    return __uint_as_float(u & 0xFFFF0000u);
}

// ---------------- K0a: histogram of destination degrees (x4 vectorized) ----------------
__global__ __launch_bounds__(256) void count_deg(
    const int* __restrict__ ei, int* __restrict__ deg)
{
    const int e4 = blockIdx.x * 256 + threadIdx.x;
    if (e4 < N_EDGES / 4) {
        const int4 v = ((const int4*)(ei + N_EDGES))[e4];
        atomicAdd(&deg[v.x], 1);
        atomicAdd(&deg[v.y], 1);
        atomicAdd(&deg[v.z], 1);
        atomicAdd(&deg[v.w], 1);
    }
}

// ---------------- K0b: hierarchical exclusive scan ----------------
__global__ __launch_bounds__(1024) void scan_local(
    const int* __restrict__ deg, int* __restrict__ off, int* __restrict__ part)
{
    __shared__ int s[1024];
    const int tid = threadIdx.x;
    const int idx = blockIdx.x * 1024 + tid;
    s[tid] = (idx < N_NODES) ? deg[idx] : 0;
    __syncthreads();
    for (int o = 1; o < 1024; o <<= 1) {
        int t = (tid >= o) ? s[tid - o] : 0;
        __syncthreads();
        s[tid] += t;
        __syncthreads();
    }
    if (idx < N_NODES) off[idx + 1] = s[tid];
    if (tid == 1023) part[blockIdx.x] = s[1023];
}

__global__ __launch_bounds__(64) void scan_part(int* __restrict__ part)
{
    const int lane = threadIdx.x;
    int v = (lane < SCAN_NBLK) ? part[lane] : 0;
    const int orig = v;
    for (int o = 1; o < 64; o <<= 1) {
        int t = __shfl_up(v, o, 64);
        if (lane >= o) v += t;
    }
    if (lane < SCAN_NBLK) part[lane] = v - orig;
}

__global__ __launch_bounds__(1024) void scan_add(
    const int* __restrict__ part, int* __restrict__ off, int* __restrict__ woff)
{
    const int idx = blockIdx.x * 1024 + threadIdx.x;
    if (idx == 0) { off[0] = 0; woff[0] = 0; }
    if (idx < N_NODES) {
        const int val = off[idx + 1] + part[blockIdx.x];
        off[idx + 1] = val;
        if (idx + 1 < N_NODES) woff[idx + 1] = val;
    }
}

// ---------------- K1: Q/K/V projections; K,V packed bf16 into one uint row ----------------
__global__ __launch_bounds__(256) void qkv_proj(
    const float* __restrict__ x,
    const float* __restrict__ WQ, const float* __restrict__ bQ,
    const float* __restrict__ WK, const float* __restrict__ bK,
    const float* __restrict__ WV, const float* __restrict__ bV,
    float* __restrict__ Q, unsigned int* __restrict__ KV)
{
    __shared__ float sWQ[DIM * DIM];
    __shared__ float sWK[DIM * DIM];
    __shared__ float sWV[DIM * DIM];
    for (int t = threadIdx.x; t < DIM * DIM; t += blockDim.x) {
        sWQ[t] = WQ[t]; sWK[t] = WK[t]; sWV[t] = WV[t];
    }
    __syncthreads();
    const int lane = threadIdx.x & 63;
    const int wave = threadIdx.x >> 6;
    const int n = blockIdx.x * 4 + wave;
    if (n >= N_NODES) return;
    float xl = x[(size_t)n * DIM + lane];
    float aq = bQ[lane], ak = bK[lane], av = bV[lane];
    #pragma unroll
    for (int k = 0; k < DIM; ++k) {
        float xv = __shfl(xl, k, 64);
        aq += xv * sWQ[k * DIM + lane];
        ak += xv * sWK[k * DIM + lane];
        av += xv * sWV[k * DIM + lane];
    }
    Q[(size_t)n * DIM + lane] = aq;
    KV[(size_t)n * DIM + lane] = f2bf(ak) | (f2bf(av) << 16);  // K lo, V hi
}

// ---------------- K2: per-edge MLP bias -> bf16x8 record scattered to CSR position ----------------
__global__ __launch_bounds__(256) void edge_mlp_scatter(
    const int* __restrict__ ei,
    const float* __restrict__ edge_attr,
    const float* __restrict__ We1, const float* __restrict__ be1,
    const float* __restrict__ We2, const float* __restrict__ be2,
    int* __restrict__ woff,
    uint4* __restrict__ bias_sorted, int* __restrict__ src_sorted)
{
    __shared__ float sW1[EDGE_DIM * EDGE_DIM];
    __shared__ float sW2[EDGE_DIM * HEADS];
    __shared__ float sb1[EDGE_DIM];
    __shared__ float sb2[HEADS];
    for (int t = threadIdx.x; t < EDGE_DIM * EDGE_DIM; t += 256) sW1[t] = We1[t];
    for (int t = threadIdx.x; t < EDGE_DIM * HEADS; t += 256) sW2[t] = We2[t];
    if (threadIdx.x < EDGE_DIM) sb1[threadIdx.x] = be1[threadIdx.x];
    if (threadIdx.x < HEADS)    sb2[threadIdx.x] = be2[threadIdx.x];
    __syncthreads();
    const int e = blockIdx.x * 256 + threadIdx.x;
    if (e >= N_EDGES) return;
    float a[EDGE_DIM];
    const float4* ar = (const float4*)(edge_attr + (size_t)e * EDGE_DIM);
    #pragma unroll
    for (int q = 0; q < EDGE_DIM / 4; ++q) {
        float4 v = ar[q];
        a[q * 4 + 0] = v.x; a[q * 4 + 1] = v.y;
        a[q * 4 + 2] = v.z; a[q * 4 + 3] = v.w;
    }
    float bias[HEADS];
    #pragma unroll
    for (int h = 0; h < HEADS; ++h) bias[h] = sb2[h];
    #pragma unroll 4
    for (int c = 0; c < EDGE_DIM; ++c) {
        float s = sb1[c];
        #pragma unroll
        for (int k = 0; k < EDGE_DIM; ++k) s += a[k] * sW1[k * EDGE_DIM + c];
        const float sil = __fdividef(s, 1.0f + __expf(-s));
        #pragma unroll
        for (int h = 0; h < HEADS; ++h) bias[h] += sil * sW2[c * HEADS + h];
    }
    const int i = ei[e];
    const int j = ei[N_EDGES + e];
    const int p = atomicAdd(&woff[j], 1);
    src_sorted[p] = i;
    uint4 br;
    br.x = f2bf(bias[0]) | (f2bf(bias[1]) << 16);
    br.y = f2bf(bias[2]) | (f2bf(bias[3]) << 16);
    br.z = f2bf(bias[4]) | (f2bf(bias[5]) << 16);
    br.w = f2bf(bias[6]) | (f2bf(bias[7]) << 16);
    bias_sorted[p] = br;
}

// ---------------- K3: per-node attention + fused output projection ----------------
// One wave per destination node, lane = dim. One packed 256B KV gather per edge.
__global__ __launch_bounds__(256) void node_attn_out(
    const int* __restrict__ off,
    const int* __restrict__ src_sorted,
    const unsigned short* __restrict__ bias_u16,
    const float* __restrict__ Q, const unsigned int* __restrict__ KV,
    const float* __restrict__ WO, const float* __restrict__ bO,
    float* __restrict__ out)
{
    __shared__ float sWO[DIM * DIM];
    for (int t = threadIdx.x; t < DIM * DIM; t += 256) sWO[t] = WO[t];
    __syncthreads();
    const int lane = threadIdx.x & 63;
    const int wave = threadIdx.x >> 6;
    const int j = blockIdx.x * 4 + wave;
    if (j >= N_NODES) return;
    const int beg = off[j], end = off[j + 1];
    const int h = lane >> 3;
    const float qv = Q[(size_t)j * DIM + lane];
    const float inv_sqrt_dk = 0.35355339059327373f;
    float num = 0.0f;
    float den = 1e-12f;
    int t = beg;
    for (; t + 3 < end; t += 4) {
        const int i0 = src_sorted[t + 0];
        const int i1 = src_sorted[t + 1];
        const int i2 = src_sorted[t + 2];
        const int i3 = src_sorted[t + 3];
        const unsigned int u0 = KV[(size_t)i0 * DIM + lane];
        const unsigned int u1 = KV[(size_t)i1 * DIM + lane];
        const unsigned int u2 = KV[(size_t)i2 * DIM + lane];
        const unsigned int u3 = KV[(size_t)i3 * DIM + lane];
        const float b0 = bf_lo((unsigned int)bias_u16[(size_t)(t + 0) * HEADS + h]);
        const float b1 = bf_lo((unsigned int)bias_u16[(size_t)(t + 1) * HEADS + h]);
        const float b2 = bf_lo((unsigned int)bias_u16[(size_t)(t + 2) * HEADS + h]);
        const float b3 = bf_lo((unsigned int)bias_u16[(size_t)(t + 3) * HEADS + h]);
        float d0 = qv * bf_lo(u0);
        float d1 = qv * bf_lo(u1);
        float d2 = qv * bf_lo(u2);
        float d3 = qv * bf_lo(u3);
        d0 += __shfl_xor(d0, 1, 64); d1 += __shfl_xor(d1, 1, 64);
        d2 += __shfl_xor(d2, 1, 64); d3 += __shfl_xor(d3, 1, 64);
        d0 += __shfl_xor(d0, 2, 64); d1 += __shfl_xor(d1, 2, 64);
        d2 += __shfl_xor(d2, 2, 64); d3 += __shfl_xor(d3, 2, 64);
        d0 += __shfl_xor(d0, 4, 64); d1 += __shfl_xor(d1, 4, 64);
        d2 += __shfl_xor(d2, 4, 64); d3 += __shfl_xor(d3, 4, 64);
        const float e0 = __expf(d0 * inv_sqrt_dk + b0);
        const float e1 = __expf(d1 * inv_sqrt_dk + b1);
        const float e2 = __expf(d2 * inv_sqrt_dk + b2);
        const float e3 = __expf(d3 * inv_sqrt_dk + b3);
        num += e0 * bf_hi(u0) + e1 * bf_hi(u1) + e2 * bf_hi(u2) + e3 * bf_hi(u3);
        den += e0 + e1 + e2 + e3;
    }
    for (; t < end; ++t) {
        const int i0 = src_sorted[t];
        const unsigned int u0 = KV[(size_t)i0 * DIM + lane];
        const float b0 = bf_lo((unsigned int)bias_u16[(size_t)t * HEADS + h]);
        float d0 = qv * bf_lo(u0);
        d0 += __shfl_xor(d0, 1, 64);
        d0 += __shfl_xor(d0, 2, 64);
        d0 += __shfl_xor(d0, 4, 64);
        const float e0 = __expf(d0 * inv_sqrt_dk + b0);
        num += e0 * bf_hi(u0);
        den += e0;
    }
    const float av = num / den;
    float acc = bO[lane];
    #pragma unroll
    for (int k = 0; k < DIM; ++k) {
        acc += __shfl(av, k, 64) * sWO[k * DIM + lane];
    }
    out[(size_t)j * DIM + lane] = acc;
}

extern "C" void kernel_launch(void* const* d_in, const int* in_sizes, int n_in,
                              void* d_out, int out_size, void* d_ws, size_t ws_size,
                              hipStream_t stream) {
    const float* x    = (const float*)d_in[0];
    const int*   ei   = (const int*)d_in[1];
    const float* ea   = (const float*)d_in[2];
    const float* WQ   = (const float*)d_in[3];
    const float* bQ   = (const float*)d_in[4];
    const float* WK   = (const float*)d_in[5];
    const float* bK   = (const float*)d_in[6];
    const float* WV   = (const float*)d_in[7];
    const float* bV   = (const float*)d_in[8];
    const float* WO   = (const float*)d_in[9];
    const float* bO   = (const float*)d_in[10];
    const float* We1  = (const float*)d_in[11];
    const float* be1  = (const float*)d_in[12];
    const float* We2  = (const float*)d_in[13];
    const float* be2  = (const float*)d_in[14];
    float* out = (float*)d_out;

    char* ws = (char*)d_ws;
    size_t off_b = 0;
    auto alloc = [&](size_t bytes) {
        void* p = ws + off_b;
        off_b += (bytes + 255) & ~(size_t)255;
        return p;
    };
    float*        Q           = (float*)alloc((size_t)N_NODES * DIM * sizeof(float));
    unsigned int* KV          = (unsigned int*)alloc((size_t)N_NODES * DIM * sizeof(unsigned int));
    uint4*        bias_sorted = (uint4*)alloc((size_t)N_EDGES * sizeof(uint4));
    int*          src_sorted  = (int*)alloc((size_t)N_EDGES * sizeof(int));
    int*          deg         = (int*)alloc((size_t)N_NODES * sizeof(int));
    int*          offs        = (int*)alloc((size_t)(N_NODES + 1) * sizeof(int));
    int*          woff        = (int*)alloc((size_t)N_NODES * sizeof(int));
    int*          part        = (int*)alloc((size_t)SCAN_NBLK * sizeof(int));

    hipMemsetAsync(deg, 0, (size_t)N_NODES * sizeof(int), stream);

    count_deg<<<(N_EDGES / 4 + 255) / 256, 256, 0, stream>>>(ei, deg);
    scan_local<<<SCAN_NBLK, 1024, 0, stream>>>(deg, offs, part);
    scan_part<<<1, 64, 0, stream>>>(part);
    scan_add<<<SCAN_NBLK, 1024, 0, stream>>>(part, offs, woff);
    qkv_proj<<<(N_NODES + 3) / 4, 256, 0, stream>>>(x, WQ, bQ, WK, bK, WV, bV, Q, KV);
    edge_mlp_scatter<<<N_EDGES / 256, 256, 0, stream>>>(ei, ea, We1, be1, We2, be2,
                                                        woff, bias_sorted, src_sorted);
    node_attn_out<<<(N_NODES + 3) / 4, 256, 0, stream>>>(offs, src_sorted,
                                                         (const unsigned short*)bias_sorted,
                                                         Q, KV, WO, bO, out);
}

// Round 6
// 429.645 us; speedup vs baseline: 14.2460x; 1.0302x over previous
//
#include <hip/hip_runtime.h>
#include <math.h>

#define N_NODES 50000
#define N_EDGES 1600000
#define DIM 64
#define HEADS 8
#define EDGE_DIM 32
#define SCAN_NBLK 49  // ceil(50000/1024)

typedef __fp16 h2 __attribute__((ext_vector_type(2)));

// ---- bf16 helpers (RNE round via bit trick; inputs are finite) ----
__device__ __forceinline__ unsigned int f2bf(float f) {
    union { float f; unsigned int u; } c; c.f = f;
    unsigned int u = c.u;
    return (u + 0x7FFFu + ((u >> 16) & 1u)) >> 16;
}
__device__ __forceinline__ float bf_lo(unsigned int u) { return __uint_as_float(u << 16); }
__device__ __forceinline__ float bf_hi(unsigned int u) { return __uint_as_float(u & 0xFFFF0000u); }

// ---------------- K_prep: pack MLP weights as half2 pairs (k-pairs) ----------------
// w1p[c*16+kk] = (We1[2kk][c], We1[2kk+1][c])   c in [0,32), kk in [0,16)
// w2p[h*16+cc] = (We2[2cc][h], We2[2cc+1][h])   h in [0,8),  cc in [0,16)
__global__ __launch_bounds__(1024) void pack_weights(
    const float* __restrict__ We1, const float* __restrict__ We2,
    h2* __restrict__ w1p, h2* __restrict__ w2p)
{
    const int t = threadIdx.x;
    if (t < 512) {
        const int c = t >> 4, kk = t & 15;
        w1p[t] = __builtin_amdgcn_cvt_pkrtz(We1[(2 * kk) * EDGE_DIM + c],
                                            We1[(2 * kk + 1) * EDGE_DIM + c]);
    } else if (t < 512 + 128) {
        const int u = t - 512;
        const int h = u >> 4, cc = u & 15;
        w2p[u] = __builtin_amdgcn_cvt_pkrtz(We2[(2 * cc) * HEADS + h],
                                            We2[(2 * cc + 1) * HEADS + h]);
    }
}

// ---------------- K0a: histogram of destination degrees (x4 vectorized) ----------------
__global__ __launch_bounds__(256) void count_deg(
    const int* __restrict__ ei, int* __restrict__ deg)
{
    const int e4 = blockIdx.x * 256 + threadIdx.x;
    if (e4 < N_EDGES / 4) {
        const int4 v = ((const int4*)(ei + N_EDGES))[e4];
        atomicAdd(&deg[v.x], 1);
        atomicAdd(&deg[v.y], 1);
        atomicAdd(&deg[v.z], 1);
        atomicAdd(&deg[v.w], 1);
    }
}

// ---------------- K0b: hierarchical exclusive scan ----------------
__global__ __launch_bounds__(1024) void scan_local(
    const int* __restrict__ deg, int* __restrict__ off, int* __restrict__ part)
{
    __shared__ int s[1024];
    const int tid = threadIdx.x;
    const int idx = blockIdx.x * 1024 + tid;
    s[tid] = (idx < N_NODES) ? deg[idx] : 0;
    __syncthreads();
    for (int o = 1; o < 1024; o <<= 1) {
        int t = (tid >= o) ? s[tid - o] : 0;
        __syncthreads();
        s[tid] += t;
        __syncthreads();
    }
    if (idx < N_NODES) off[idx + 1] = s[tid];
    if (tid == 1023) part[blockIdx.x] = s[1023];
}

__global__ __launch_bounds__(64) void scan_part(int* __restrict__ part)
{
    const int lane = threadIdx.x;
    int v = (lane < SCAN_NBLK) ? part[lane] : 0;
    const int orig = v;
    for (int o = 1; o < 64; o <<= 1) {
        int t = __shfl_up(v, o, 64);
        if (lane >= o) v += t;
    }
    if (lane < SCAN_NBLK) part[lane] = v - orig;
}

__global__ __launch_bounds__(1024) void scan_add(
    const int* __restrict__ part, int* __restrict__ off, int* __restrict__ woff)
{
    const int idx = blockIdx.x * 1024 + threadIdx.x;
    if (idx == 0) { off[0] = 0; woff[0] = 0; }
    if (idx < N_NODES) {
        const int val = off[idx + 1] + part[blockIdx.x];
        off[idx + 1] = val;
        if (idx + 1 < N_NODES) woff[idx + 1] = val;
    }
}

// ---------------- K1: Q/K/V projections; K,V packed bf16 into one uint row ----------------
__global__ __launch_bounds__(256) void qkv_proj(
    const float* __restrict__ x,
    const float* __restrict__ WQ, const float* __restrict__ bQ,
    const float* __restrict__ WK, const float* __restrict__ bK,
    const float* __restrict__ WV, const float* __restrict__ bV,
    float* __restrict__ Q, unsigned int* __restrict__ KV)
{
    __shared__ float sWQ[DIM * DIM];
    __shared__ float sWK[DIM * DIM];
    __shared__ float sWV[DIM * DIM];
    for (int t = threadIdx.x; t < DIM * DIM; t += blockDim.x) {
        sWQ[t] = WQ[t]; sWK[t] = WK[t]; sWV[t] = WV[t];
    }
    __syncthreads();
    const int lane = threadIdx.x & 63;
    const int wave = threadIdx.x >> 6;
    const int n = blockIdx.x * 4 + wave;
    if (n >= N_NODES) return;
    float xl = x[(size_t)n * DIM + lane];
    float aq = bQ[lane], ak = bK[lane], av = bV[lane];
    #pragma unroll
    for (int k = 0; k < DIM; ++k) {
        float xv = __shfl(xl, k, 64);
        aq += xv * sWQ[k * DIM + lane];
        ak += xv * sWK[k * DIM + lane];
        av += xv * sWV[k * DIM + lane];
    }
    Q[(size_t)n * DIM + lane] = aq;
    KV[(size_t)n * DIM + lane] = f2bf(ak) | (f2bf(av) << 16);  // K lo, V hi
}

// ---------------- K2: per-edge MLP via f16 dot2, weights on scalar pipe ----------------
// No LDS. Weight/bias operands are wave-uniform const loads -> s_load (SGPR
// operand in v_dot2), so the VALU pays only the dot2 itself (2 MAC/instr).
__global__ __launch_bounds__(256) void edge_mlp_scatter(
    const int* __restrict__ ei,
    const float* __restrict__ edge_attr,
    const h2* __restrict__ w1p, const float* __restrict__ be1,
    const h2* __restrict__ w2p, const float* __restrict__ be2,
    int* __restrict__ woff,
    uint4* __restrict__ bias_sorted, int* __restrict__ src_sorted)
{
    const int e = blockIdx.x * 256 + threadIdx.x;
    if (e >= N_EDGES) return;
    // load edge_attr row and pack to f16 pairs
    float a[EDGE_DIM];
    const float4* ar = (const float4*)(edge_attr + (size_t)e * EDGE_DIM);
    #pragma unroll
    for (int q = 0; q < EDGE_DIM / 4; ++q) {
        float4 v = ar[q];
        a[q * 4 + 0] = v.x; a[q * 4 + 1] = v.y;
        a[q * 4 + 2] = v.z; a[q * 4 + 3] = v.w;
    }
    h2 a2[EDGE_DIM / 2];
    #pragma unroll
    for (int kk = 0; kk < EDGE_DIM / 2; ++kk)
        a2[kk] = __builtin_amdgcn_cvt_pkrtz(a[2 * kk], a[2 * kk + 1]);
    // layer 1 + SiLU
    float sil[EDGE_DIM];
    #pragma unroll 8
    for (int c = 0; c < EDGE_DIM; ++c) {
        float s = be1[c];
        #pragma unroll
        for (int kk = 0; kk < EDGE_DIM / 2; ++kk)
            s = __builtin_amdgcn_fdot2(a2[kk], w1p[c * 16 + kk], s, false);
        sil[c] = __fdividef(s, 1.0f + __expf(-s));
    }
    h2 s2[EDGE_DIM / 2];
    #pragma unroll
    for (int cc = 0; cc < EDGE_DIM / 2; ++cc)
        s2[cc] = __builtin_amdgcn_cvt_pkrtz(sil[2 * cc], sil[2 * cc + 1]);
    // layer 2
    float bias[HEADS];
    #pragma unroll
    for (int h = 0; h < HEADS; ++h) {
        float b = be2[h];
        #pragma unroll
        for (int cc = 0; cc < EDGE_DIM / 2; ++cc)
            b = __builtin_amdgcn_fdot2(s2[cc], w2p[h * 16 + cc], b, false);
        bias[h] = b;
    }
    const int i = ei[e];
    const int j = ei[N_EDGES + e];
    const int p = atomicAdd(&woff[j], 1);
    src_sorted[p] = i;
    uint4 br;
    br.x = f2bf(bias[0]) | (f2bf(bias[1]) << 16);
    br.y = f2bf(bias[2]) | (f2bf(bias[3]) << 16);
    br.z = f2bf(bias[4]) | (f2bf(bias[5]) << 16);
    br.w = f2bf(bias[6]) | (f2bf(bias[7]) << 16);
    bias_sorted[p] = br;
}

// ---------------- K3: per-node attention + fused output projection ----------------
__global__ __launch_bounds__(256) void node_attn_out(
    const int* __restrict__ off,
    const int* __restrict__ src_sorted,
    const unsigned short* __restrict__ bias_u16,
    const float* __restrict__ Q, const unsigned int* __restrict__ KV,
    const float* __restrict__ WO, const float* __restrict__ bO,
    float* __restrict__ out)
{
    __shared__ float sWO[DIM * DIM];
    for (int t = threadIdx.x; t < DIM * DIM; t += 256) sWO[t] = WO[t];
    __syncthreads();
    const int lane = threadIdx.x & 63;
    const int wave = threadIdx.x >> 6;
    const int j = blockIdx.x * 4 + wave;
    if (j >= N_NODES) return;
    const int beg = off[j], end = off[j + 1];
    const int h = lane >> 3;
    const float qv = Q[(size_t)j * DIM + lane];
    const float inv_sqrt_dk = 0.35355339059327373f;
    float num = 0.0f;
    float den = 1e-12f;
    int t = beg;
    for (; t + 3 < end; t += 4) {
        const int i0 = src_sorted[t + 0];
        const int i1 = src_sorted[t + 1];
        const int i2 = src_sorted[t + 2];
        const int i3 = src_sorted[t + 3];
        const unsigned int u0 = KV[(size_t)i0 * DIM + lane];
        const unsigned int u1 = KV[(size_t)i1 * DIM + lane];
        const unsigned int u2 = KV[(size_t)i2 * DIM + lane];
        const unsigned int u3 = KV[(size_t)i3 * DIM + lane];
        const float b0 = bf_lo((unsigned int)bias_u16[(size_t)(t + 0) * HEADS + h]);
        const float b1 = bf_lo((unsigned int)bias_u16[(size_t)(t + 1) * HEADS + h]);
        const float b2 = bf_lo((unsigned int)bias_u16[(size_t)(t + 2) * HEADS + h]);
        const float b3 = bf_lo((unsigned int)bias_u16[(size_t)(t + 3) * HEADS + h]);
        float d0 = qv * bf_lo(u0);
        float d1 = qv * bf_lo(u1);
        float d2 = qv * bf_lo(u2);
        float d3 = qv * bf_lo(u3);
        d0 += __shfl_xor(d0, 1, 64); d1 += __shfl_xor(d1, 1, 64);
        d2 += __shfl_xor(d2, 1, 64); d3 += __shfl_xor(d3, 1, 64);
        d0 += __shfl_xor(d0, 2, 64); d1 += __shfl_xor(d1, 2, 64);
        d2 += __shfl_xor(d2, 2, 64); d3 += __shfl_xor(d3, 2, 64);
        d0 += __shfl_xor(d0, 4, 64); d1 += __shfl_xor(d1, 4, 64);
        d2 += __shfl_xor(d2, 4, 64); d3 += __shfl_xor(d3, 4, 64);
        const float e0 = __expf(d0 * inv_sqrt_dk + b0);
        const float e1 = __expf(d1 * inv_sqrt_dk + b1);
        const float e2 = __expf(d2 * inv_sqrt_dk + b2);
        const float e3 = __expf(d3 * inv_sqrt_dk + b3);
        num += e0 * bf_hi(u0) + e1 * bf_hi(u1) + e2 * bf_hi(u2) + e3 * bf_hi(u3);
        den += e0 + e1 + e2 + e3;
    }
    for (; t < end; ++t) {
        const int i0 = src_sorted[t];
        const unsigned int u0 = KV[(size_t)i0 * DIM + lane];
        const float b0 = bf_lo((unsigned int)bias_u16[(size_t)t * HEADS + h]);
        float d0 = qv * bf_lo(u0);
        d0 += __shfl_xor(d0, 1, 64);
        d0 += __shfl_xor(d0, 2, 64);
        d0 += __shfl_xor(d0, 4, 64);
        const float e0 = __expf(d0 * inv_sqrt_dk + b0);
        num += e0 * bf_hi(u0);
        den += e0;
    }
    const float av = num / den;
    float acc = bO[lane];
    #pragma unroll
    for (int k = 0; k < DIM; ++k) {
        acc += __shfl(av, k, 64) * sWO[k * DIM + lane];
    }
    out[(size_t)j * DIM + lane] = acc;
}

extern "C" void kernel_launch(void* const* d_in, const int* in_sizes, int n_in,
                              void* d_out, int out_size, void* d_ws, size_t ws_size,
                              hipStream_t stream) {
    const float* x    = (const float*)d_in[0];
    const int*   ei   = (const int*)d_in[1];
    const float* ea   = (const float*)d_in[2];
    const float* WQ   = (const float*)d_in[3];
    const float* bQ   = (const float*)d_in[4];
    const float* WK   = (const float*)d_in[5];
    const float* bK   = (const float*)d_in[6];
    const float* WV   = (const float*)d_in[7];
    const float* bV   = (const float*)d_in[8];
    const float* WO   = (const float*)d_in[9];
    const float* bO   = (const float*)d_in[10];
    const float* We1  = (const float*)d_in[11];
    const float* be1  = (const float*)d_in[12];
    const float* We2  = (const float*)d_in[13];
    const float* be2  = (const float*)d_in[14];
    float* out = (float*)d_out;

    char* ws = (char*)d_ws;
    size_t off_b = 0;
    auto alloc = [&](size_t bytes) {
        void* p = ws + off_b;
        off_b += (bytes + 255) & ~(size_t)255;
        return p;
    };
    float*        Q           = (float*)alloc((size_t)N_NODES * DIM * sizeof(float));
    unsigned int* KV          = (unsigned int*)alloc((size_t)N_NODES * DIM * sizeof(unsigned int));
    uint4*        bias_sorted = (uint4*)alloc((size_t)N_EDGES * sizeof(uint4));
    int*          src_sorted  = (int*)alloc((size_t)N_EDGES * sizeof(int));
    int*          deg         = (int*)alloc((size_t)N_NODES * sizeof(int));
    int*          offs        = (int*)alloc((size_t)(N_NODES + 1) * sizeof(int));
    int*          woff        = (int*)alloc((size_t)N_NODES * sizeof(int));
    int*          part        = (int*)alloc((size_t)SCAN_NBLK * sizeof(int));
    h2*           w1p         = (h2*)alloc(512 * sizeof(h2));
    h2*           w2p         = (h2*)alloc(128 * sizeof(h2));

    (void)hipMemsetAsync(deg, 0, (size_t)N_NODES * sizeof(int), stream);

    pack_weights<<<1, 1024, 0, stream>>>(We1, We2, w1p, w2p);
    count_deg<<<(N_EDGES / 4 + 255) / 256, 256, 0, stream>>>(ei, deg);
    scan_local<<<SCAN_NBLK, 1024, 0, stream>>>(deg, offs, part);
    scan_part<<<1, 64, 0, stream>>>(part);
    scan_add<<<SCAN_NBLK, 1024, 0, stream>>>(part, offs, woff);
    qkv_proj<<<(N_NODES + 3) / 4, 256, 0, stream>>>(x, WQ, bQ, WK, bK, WV, bV, Q, KV);
    edge_mlp_scatter<<<N_EDGES / 256, 256, 0, stream>>>(ei, ea, w1p, be1, w2p, be2,
                                                        woff, bias_sorted, src_sorted);
    node_attn_out<<<(N_NODES + 3) / 4, 256, 0, stream>>>(offs, src_sorted,
                                                         (const unsigned short*)bias_sorted,
                                                         Q, KV, WO, bO, out);
}